// Round 1
// baseline (480.527 us; speedup 1.0000x reference)
//
#include <hip/hip_runtime.h>
#include <math.h>

typedef __attribute__((ext_vector_type(8))) short short8;
typedef __attribute__((ext_vector_type(4))) short short4v;
typedef __attribute__((ext_vector_type(4))) float f32x4;
typedef unsigned short ushort_t;

#define NT 4096      // tokens (B*S)
#define DM 1024      // d_model
#define DF 4096      // d_ff
#define NE 8         // experts
#define LDSS 40      // LDS row stride in bf16 elements (80B: spreads bank conflicts)

static __device__ __forceinline__ short f2bf(float f) {
  union { float f; unsigned u; } v; v.f = f;
  unsigned r = (v.u + 0x7fffu + ((v.u >> 16) & 1u)) >> 16;  // RNE
  return (short)r;
}

// ---------------- gating: one wave per token ----------------
__global__ __launch_bounds__(64) void gate_k(const float* __restrict__ x,
                                             const float* __restrict__ Wg,
                                             int* __restrict__ te,
                                             float* __restrict__ tw) {
  int t = blockIdx.x;
  int l = threadIdx.x;
  float a0=0,a1=0,a2=0,a3=0,a4=0,a5=0,a6=0,a7=0;
  const float* xr = x + (size_t)t * DM;
  for (int k = l; k < DM; k += 64) {
    float xv = xr[k];
    const float4* wp = (const float4*)(Wg + k * 8);
    float4 w0 = wp[0], w1 = wp[1];
    a0 += xv * w0.x; a1 += xv * w0.y; a2 += xv * w0.z; a3 += xv * w0.w;
    a4 += xv * w1.x; a5 += xv * w1.y; a6 += xv * w1.z; a7 += xv * w1.w;
  }
#pragma unroll
  for (int s = 32; s >= 1; s >>= 1) {
    a0 += __shfl_down(a0, s); a1 += __shfl_down(a1, s);
    a2 += __shfl_down(a2, s); a3 += __shfl_down(a3, s);
    a4 += __shfl_down(a4, s); a5 += __shfl_down(a5, s);
    a6 += __shfl_down(a6, s); a7 += __shfl_down(a7, s);
  }
  if (l == 0) {
    float lg[8] = {a0,a1,a2,a3,a4,a5,a6,a7};
    float m = lg[0];
#pragma unroll
    for (int e = 1; e < 8; ++e) m = fmaxf(m, lg[e]);
    float p[8], s = 0.f;
#pragma unroll
    for (int e = 0; e < 8; ++e) { p[e] = expf(lg[e] - m); s += p[e]; }
#pragma unroll
    for (int e = 0; e < 8; ++e) p[e] /= s;
    int i0 = 0; float v0 = p[0];
#pragma unroll
    for (int e = 1; e < 8; ++e) if (p[e] > v0) { v0 = p[e]; i0 = e; }
    int i1 = -1; float v1 = -1.f;
#pragma unroll
    for (int e = 0; e < 8; ++e) {
      if (e == i0) continue;
      if (p[e] > v1) { v1 = p[e]; i1 = e; }
    }
    float norm = v0 + v1 + 1e-8f;
    te[t*2]   = i0; te[t*2+1] = i1;
    tw[t*2]   = v0 / norm; tw[t*2+1] = v1 / norm;
  }
}

// ---------------- routing: build per-expert token lists ----------------
__global__ __launch_bounds__(256) void route_k(const int* __restrict__ te,
                                               const float* __restrict__ tw,
                                               int* __restrict__ meta,
                                               int* __restrict__ lt,
                                               float* __restrict__ lw) {
  int i = blockIdx.x * 256 + threadIdx.x;
  if (i >= NT * 2) return;
  int e = te[i];
  float w = tw[i];
  int pos = atomicAdd(&meta[e], 1);
  lt[e * NT + pos] = i >> 1;
  lw[e * NT + pos] = w;
}

// ---------------- finalize: pad lists to 128, compute row bases ----------------
__global__ __launch_bounds__(256) void finalize_k(int* __restrict__ meta,
                                                  int* __restrict__ lt,
                                                  float* __restrict__ lw) {
  __shared__ int s_cnt[8], s_pc[8];
  if (threadIdx.x == 0) {
    int base = 0;
    for (int e = 0; e < 8; ++e) {
      int c = meta[e];
      int pc = (c + 127) & ~127;
      s_cnt[e] = c; s_pc[e] = pc;
      meta[8 + e] = pc;
      meta[16 + e] = base;
      base += pc;
    }
  }
  __syncthreads();
  for (int e = 0; e < 8; ++e) {
    int c = s_cnt[e], pc = s_pc[e];
    for (int i = c + (int)threadIdx.x; i < pc; i += 256) {
      lt[e * NT + i] = 0;      // dummy token
      lw[e * NT + i] = 0.f;    // zero weight -> contributes nothing
    }
  }
}

// ---------------- FFN1: H = gelu(X_gathered @ W1[e] + b1[e]) (bf16 out) ----------------
__global__ __launch_bounds__(256) void ffn1_k(const float* __restrict__ x,
                                              const float* __restrict__ W1,
                                              const float* __restrict__ b1,
                                              const int* __restrict__ lt,
                                              const int* __restrict__ meta,
                                              ushort_t* __restrict__ H) {
  const int e = blockIdx.z, mt = blockIdx.y, ntile = blockIdx.x;
  const int pc = meta[8 + e];
  if (mt * 128 >= pc) return;
  const int rbase = meta[16 + e];

  __shared__ short As[128 * LDSS];
  __shared__ short Bs[128 * LDSS];
  __shared__ int s_tok[128];

  const int tid = threadIdx.x;
  if (tid < 128) s_tok[tid] = lt[e * NT + mt * 128 + tid];
  __syncthreads();

  const float* W1e = W1 + (size_t)e * DM * DF;
  const int lane = tid & 63, wave = tid >> 6;
  const int wm = wave >> 1, wn = wave & 1;
  const int l15 = lane & 15, l4 = lane >> 4;

  int aoff[4], boff[4];
#pragma unroll
  for (int i = 0; i < 4; ++i) {
    aoff[i] = (wm * 64 + i * 16 + l15) * LDSS + l4 * 8;
    boff[i] = (wn * 64 + i * 16 + l15) * LDSS + l4 * 8;
  }

  f32x4 acc[4][4];
#pragma unroll
  for (int mi = 0; mi < 4; ++mi)
#pragma unroll
    for (int ni = 0; ni < 4; ++ni) acc[mi][ni] = 0.f;

  for (int k0 = 0; k0 < DM; k0 += 32) {
    __syncthreads();
    // stage A: 128 rows x 32 k (fp32 -> bf16), gathered tokens
#pragma unroll
    for (int i = 0; i < 4; ++i) {
      int c = tid + 256 * i;
      int r = c >> 3, kc = c & 7;
      const float4 v = *(const float4*)(x + (size_t)s_tok[r] * DM + k0 + kc * 4);
      short4v pkt = { f2bf(v.x), f2bf(v.y), f2bf(v.z), f2bf(v.w) };
      *(short4v*)&As[r * LDSS + kc * 4] = pkt;
    }
    // stage B^T: 128 n x 32 k; column chunks 4k x 1n (dword-coalesced)
#pragma unroll
    for (int j = 0; j < 4; ++j) {
      int c = tid + 256 * j;
      int n = c & 127, kg = c >> 7;
      const float* col = W1e + (size_t)(k0 + kg * 4) * DF + ntile * 128 + n;
      short4v pkt = { f2bf(col[0]), f2bf(col[DF]), f2bf(col[2 * DF]), f2bf(col[3 * DF]) };
      *(short4v*)&Bs[n * LDSS + kg * 4] = pkt;
    }
    __syncthreads();

    short8 af[4], bfr[4];
#pragma unroll
    for (int i = 0; i < 4; ++i) {
      af[i]  = *(const short8*)&As[aoff[i]];
      bfr[i] = *(const short8*)&Bs[boff[i]];
    }
#pragma unroll
    for (int mi = 0; mi < 4; ++mi)
#pragma unroll
      for (int ni = 0; ni < 4; ++ni)
        acc[mi][ni] = __builtin_amdgcn_mfma_f32_16x16x32_bf16(af[mi], bfr[ni], acc[mi][ni], 0, 0, 0);
  }

  // epilogue: + b1, exact GELU, store bf16
#pragma unroll
  for (int mi = 0; mi < 4; ++mi) {
#pragma unroll
    for (int ni = 0; ni < 4; ++ni) {
      int gn = ntile * 128 + wn * 64 + ni * 16 + l15;
      float bias = b1[e * DF + gn];
      int r0 = mt * 128 + wm * 64 + mi * 16 + l4 * 4;
#pragma unroll
      for (int j = 0; j < 4; ++j) {
        float v = acc[mi][ni][j] + bias;
        v = 0.5f * v * (1.0f + erff(v * 0.70710678118654752f));
        H[(size_t)(rbase + r0 + j) * DF + gn] = (ushort_t)f2bf(v);
      }
    }
  }
}

// ---------------- FFN2: out[tok] += w * (H @ W2[e] + b2[e]) ----------------
__global__ __launch_bounds__(256) void ffn2_k(const ushort_t* __restrict__ H,
                                              const float* __restrict__ W2,
                                              const float* __restrict__ b2,
                                              const int* __restrict__ lt,
                                              const float* __restrict__ lw,
                                              const int* __restrict__ meta,
                                              float* __restrict__ out) {
  const int e = blockIdx.z, mt = blockIdx.y, ntile = blockIdx.x;
  const int pc = meta[8 + e];
  if (mt * 128 >= pc) return;
  const int rbase = meta[16 + e];

  __shared__ short As[128 * LDSS];
  __shared__ short Bs[128 * LDSS];
  __shared__ int s_tok[128];
  __shared__ float s_w[128];

  const int tid = threadIdx.x;
  if (tid < 128) {
    s_tok[tid] = lt[e * NT + mt * 128 + tid];
    s_w[tid]   = lw[e * NT + mt * 128 + tid];
  }

  const float* W2e = W2 + (size_t)e * DF * DM;
  const int lane = tid & 63, wave = tid >> 6;
  const int wm = wave >> 1, wn = wave & 1;
  const int l15 = lane & 15, l4 = lane >> 4;

  int aoff[4], boff[4];
#pragma unroll
  for (int i = 0; i < 4; ++i) {
    aoff[i] = (wm * 64 + i * 16 + l15) * LDSS + l4 * 8;
    boff[i] = (wn * 64 + i * 16 + l15) * LDSS + l4 * 8;
  }

  f32x4 acc[4][4];
#pragma unroll
  for (int mi = 0; mi < 4; ++mi)
#pragma unroll
    for (int ni = 0; ni < 4; ++ni) acc[mi][ni] = 0.f;

  for (int k0 = 0; k0 < DF; k0 += 32) {
    __syncthreads();
    // stage A: H rows (already bf16), 16B chunks
#pragma unroll
    for (int i = 0; i < 2; ++i) {
      int c = tid + 256 * i;
      int r = c >> 2, kc8 = c & 3;
      short8 v = *(const short8*)(H + (size_t)(rbase + mt * 128 + r) * DF + k0 + kc8 * 8);
      *(short8*)&As[r * LDSS + kc8 * 8] = v;
    }
    // stage B^T: W2 column chunks
#pragma unroll
    for (int j = 0; j < 4; ++j) {
      int c = tid + 256 * j;
      int n = c & 127, kg = c >> 7;
      const float* col = W2e + (size_t)(k0 + kg * 4) * DM + ntile * 128 + n;
      short4v pkt = { f2bf(col[0]), f2bf(col[DM]), f2bf(col[2 * DM]), f2bf(col[3 * DM]) };
      *(short4v*)&Bs[n * LDSS + kg * 4] = pkt;
    }
    __syncthreads();

    short8 af[4], bfr[4];
#pragma unroll
    for (int i = 0; i < 4; ++i) {
      af[i]  = *(const short8*)&As[aoff[i]];
      bfr[i] = *(const short8*)&Bs[boff[i]];
    }
#pragma unroll
    for (int mi = 0; mi < 4; ++mi)
#pragma unroll
      for (int ni = 0; ni < 4; ++ni)
        acc[mi][ni] = __builtin_amdgcn_mfma_f32_16x16x32_bf16(af[mi], bfr[ni], acc[mi][ni], 0, 0, 0);
  }

  // epilogue: weighted scatter-add (exactly 2 commutative adds per out element)
#pragma unroll
  for (int mi = 0; mi < 4; ++mi) {
#pragma unroll
    for (int ni = 0; ni < 4; ++ni) {
      int gn = ntile * 128 + wn * 64 + ni * 16 + l15;
      float bias = b2[e * DM + gn];
      int r0 = wm * 64 + mi * 16 + l4 * 4;
#pragma unroll
      for (int j = 0; j < 4; ++j) {
        int r = r0 + j;
        float w = s_w[r];
        int tok = s_tok[r];
        atomicAdd(out + (size_t)tok * DM + gn, w * (acc[mi][ni][j] + bias));
      }
    }
  }
}

extern "C" void kernel_launch(void* const* d_in, const int* in_sizes, int n_in,
                              void* d_out, int out_size, void* d_ws, size_t ws_size,
                              hipStream_t stream) {
  const float* x  = (const float*)d_in[0];
  const float* Wg = (const float*)d_in[1];
  const float* W1 = (const float*)d_in[2];
  const float* b1 = (const float*)d_in[3];
  const float* W2 = (const float*)d_in[4];
  const float* b2 = (const float*)d_in[5];
  float* out = (float*)d_out;

  char* ws = (char*)d_ws;
  int*   meta = (int*)ws;                                   // cnt[8], pc[8], base[8]
  int*   te   = (int*)(ws + 128);                           // [NT*2]
  float* tw   = (float*)(ws + 128 + 32768);                 // [NT*2]
  int*   lt   = (int*)(ws + 128 + 65536);                   // [NE*NT]
  float* lw   = (float*)(ws + 128 + 65536 + 131072);        // [NE*NT]
  ushort_t* H = (ushort_t*)(ws + 524288);                   // [<=9216][DF] bf16

  hipMemsetAsync(meta, 0, 128, stream);
  hipMemsetAsync(out, 0, (size_t)NT * DM * sizeof(float), stream);

  gate_k<<<NT, 64, 0, stream>>>(x, Wg, te, tw);
  route_k<<<(NT * 2) / 256, 256, 0, stream>>>(te, tw, meta, lt, lw);
  finalize_k<<<1, 256, 0, stream>>>(meta, lt, lw);
  ffn1_k<<<dim3(DF / 128, NT / 128, NE), 256, 0, stream>>>(x, W1, b1, lt, meta, H);
  ffn2_k<<<dim3(DM / 128, NT / 128, NE), 256, 0, stream>>>(H, W2, b2, lt, lw, meta, out);
}

// Round 2
// 395.334 us; speedup vs baseline: 1.2155x; 1.2155x over previous
//
#include <hip/hip_runtime.h>
#include <math.h>

typedef __attribute__((ext_vector_type(8))) short short8;
typedef __attribute__((ext_vector_type(4))) float f32x4;
typedef unsigned short u16;

#define NT 4096      // tokens (B*S)
#define DM 1024      // d_model
#define DF 4096      // d_ff
#define NE 8         // experts
#define HROWS 9216   // max padded rows: 8192 + 8*128

static __device__ __forceinline__ u16 f2bf(float f) {
  union { float f; unsigned u; } v; v.f = f;
  return (u16)((v.u + 0x7fffu + ((v.u >> 16) & 1u)) >> 16);  // RNE
}

static __device__ __forceinline__ void gload16(const void* g, void* l) {
  __builtin_amdgcn_global_load_lds((const __attribute__((address_space(1))) void*)g,
                                   (__attribute__((address_space(3))) void*)l, 16, 0, 0);
}

// ---------------- gating: one wave per token, 4 tokens/block ----------------
__global__ __launch_bounds__(256) void gate_k(const float* __restrict__ x,
                                              const float* __restrict__ Wg,
                                              int* __restrict__ te,
                                              float* __restrict__ tw) {
  int t = blockIdx.x * 4 + (threadIdx.x >> 6);
  int l = threadIdx.x & 63;
  float a0=0,a1=0,a2=0,a3=0,a4=0,a5=0,a6=0,a7=0;
  const float* xr = x + (size_t)t * DM;
  for (int k = l; k < DM; k += 64) {
    float xv = xr[k];
    const float4* wp = (const float4*)(Wg + k * 8);
    float4 w0 = wp[0], w1 = wp[1];
    a0 += xv * w0.x; a1 += xv * w0.y; a2 += xv * w0.z; a3 += xv * w0.w;
    a4 += xv * w1.x; a5 += xv * w1.y; a6 += xv * w1.z; a7 += xv * w1.w;
  }
#pragma unroll
  for (int s = 32; s >= 1; s >>= 1) {
    a0 += __shfl_down(a0, s); a1 += __shfl_down(a1, s);
    a2 += __shfl_down(a2, s); a3 += __shfl_down(a3, s);
    a4 += __shfl_down(a4, s); a5 += __shfl_down(a5, s);
    a6 += __shfl_down(a6, s); a7 += __shfl_down(a7, s);
  }
  if (l == 0) {
    float lg[8] = {a0,a1,a2,a3,a4,a5,a6,a7};
    float m = lg[0];
#pragma unroll
    for (int e = 1; e < 8; ++e) m = fmaxf(m, lg[e]);
    float p[8], s = 0.f;
#pragma unroll
    for (int e = 0; e < 8; ++e) { p[e] = expf(lg[e] - m); s += p[e]; }
#pragma unroll
    for (int e = 0; e < 8; ++e) p[e] /= s;
    int i0 = 0; float v0 = p[0];
#pragma unroll
    for (int e = 1; e < 8; ++e) if (p[e] > v0) { v0 = p[e]; i0 = e; }
    int i1 = -1; float v1 = -1.f;
#pragma unroll
    for (int e = 0; e < 8; ++e) {
      if (e == i0) continue;
      if (p[e] > v1) { v1 = p[e]; i1 = e; }
    }
    float norm = v0 + v1 + 1e-8f;
    te[t*2]   = i0; te[t*2+1] = i1;
    tw[t*2]   = v0 / norm; tw[t*2+1] = v1 / norm;
  }
}

// ---------------- routing ----------------
__global__ __launch_bounds__(256) void route_k(const int* __restrict__ te,
                                               const float* __restrict__ tw,
                                               int* __restrict__ meta,
                                               int* __restrict__ lt,
                                               float* __restrict__ lw) {
  int i = blockIdx.x * 256 + threadIdx.x;
  if (i >= NT * 2) return;
  int e = te[i];
  float w = tw[i];
  int pos = atomicAdd(&meta[e], 1);
  lt[e * NT + pos] = i;        // fused token*2 + slot
  lw[e * NT + pos] = w;
}

__global__ __launch_bounds__(256) void finalize_k(int* __restrict__ meta,
                                                  int* __restrict__ lt,
                                                  float* __restrict__ lw) {
  __shared__ int s_cnt[8], s_pc[8];
  if (threadIdx.x == 0) {
    int base = 0;
    for (int e = 0; e < 8; ++e) {
      int c = meta[e];
      int pc = (c + 127) & ~127;
      s_cnt[e] = c; s_pc[e] = pc;
      meta[8 + e] = pc;
      meta[16 + e] = base;
      base += pc;
    }
  }
  __syncthreads();
  for (int e = 0; e < 8; ++e) {
    int c = s_cnt[e], pc = s_pc[e];
    for (int i = c + (int)threadIdx.x; i < pc; i += 256) {
      lt[e * NT + i] = 2 * NT;   // dummy -> trash Y row; ffn1 clamps gather
      lw[e * NT + i] = 0.f;
    }
  }
}

// ---------------- prepass: x -> bf16 ----------------
__global__ __launch_bounds__(256) void prep_x(const float* __restrict__ x, u16* __restrict__ xbf) {
  size_t i = (size_t)blockIdx.x * 256 + threadIdx.x;     // 8-elem chunk id
  const float4* p = (const float4*)(x + i * 8);
  float4 a = p[0], b = p[1];
  short8 o = { (short)f2bf(a.x), (short)f2bf(a.y), (short)f2bf(a.z), (short)f2bf(a.w),
               (short)f2bf(b.x), (short)f2bf(b.y), (short)f2bf(b.z), (short)f2bf(b.w) };
  *(short8*)(xbf + i * 8) = o;
}

// ---------------- prepass: W [E][K][N] fp32 -> [E][N][K] bf16 ----------------
__global__ __launch_bounds__(256) void prep_wT(const float* __restrict__ in,
                                               u16* __restrict__ out, int K, int N) {
  const int e = blockIdx.z;
  const int n0 = blockIdx.x * 64, k0 = blockIdx.y * 64;
  const float* ie = in + (size_t)e * K * N;
  u16* oe = out + (size_t)e * K * N;
  __shared__ u16 t[64 * 72];
  const int tid = threadIdx.x;
  const int kr = tid >> 4, nq = (tid & 15) * 4;
#pragma unroll
  for (int it = 0; it < 4; ++it) {
    int k = it * 16 + kr;
    float4 v = *(const float4*)(ie + (size_t)(k0 + k) * N + n0 + nq);
    t[(nq + 0) * 72 + k] = f2bf(v.x);
    t[(nq + 1) * 72 + k] = f2bf(v.y);
    t[(nq + 2) * 72 + k] = f2bf(v.z);
    t[(nq + 3) * 72 + k] = f2bf(v.w);
  }
  __syncthreads();
#pragma unroll
  for (int it = 0; it < 2; ++it) {
    int idx = it * 256 + tid;
    int n = idx >> 3, kc = idx & 7;
    short8 v = *(const short8*)&t[n * 72 + kc * 8];
    *(short8*)(oe + (size_t)(n0 + n) * K + k0 + kc * 8) = v;
  }
}

// ---------------- FFN1: H = gelu(Xg @ W1 + b1), m97-style ----------------
__global__ __launch_bounds__(256) void ffn1_k(const u16* __restrict__ xbf,
                                              const u16* __restrict__ W1T,
                                              const float* __restrict__ b1,
                                              const int* __restrict__ lt,
                                              const int* __restrict__ meta,
                                              u16* __restrict__ H) {
  const int e = blockIdx.z, mt = blockIdx.y, nt = blockIdx.x;
  const int pc = meta[8 + e];
  if (mt * 128 >= pc) return;
  const int rbase = meta[16 + e];

  __shared__ u16 As[128 * 32];
  __shared__ u16 Bs[128 * 32];

  const int tid = threadIdx.x, lane = tid & 63, wv = tid >> 6;
  const int wm = wv >> 1, wn = wv & 1, l15 = lane & 15, l4 = lane >> 4;

  const u16* pa[2]; const u16* pb[2]; u16* la[2]; u16* lb[2];
#pragma unroll
  for (int it = 0; it < 2; ++it) {
    int idx = it * 256 + tid;
    int r = idx >> 2, s = idx & 3;
    int kg = s ^ ((r >> 1) & 3);                     // source-side XOR swizzle
    int tok = lt[e * NT + mt * 128 + r] >> 1;
    if (tok >= NT) tok = 0;                          // dummy row clamp
    pa[it] = xbf + (size_t)tok * DM + kg * 8;
    pb[it] = W1T + ((size_t)e * DF + nt * 128 + r) * DM + kg * 8;
    la[it] = As + (it * 256 + wv * 64) * 8;          // wave-uniform dest
    lb[it] = Bs + (it * 256 + wv * 64) * 8;
  }

  int aoff[4], boff[4];
#pragma unroll
  for (int i = 0; i < 4; ++i) {
    int ra = wm * 64 + i * 16 + l15;
    aoff[i] = ra * 32 + (l4 ^ ((ra >> 1) & 3)) * 8;  // swizzled read
    int rb = wn * 64 + i * 16 + l15;
    boff[i] = rb * 32 + (l4 ^ ((rb >> 1) & 3)) * 8;
  }

  f32x4 acc[4][4];
#pragma unroll
  for (int mi = 0; mi < 4; ++mi)
#pragma unroll
    for (int ni = 0; ni < 4; ++ni) acc[mi][ni] = 0.f;

  for (int ks = 0; ks < DM / 32; ++ks) {
    __syncthreads();
    gload16(pa[0], la[0]); gload16(pa[1], la[1]);
    gload16(pb[0], lb[0]); gload16(pb[1], lb[1]);
    pa[0] += 32; pa[1] += 32; pb[0] += 32; pb[1] += 32;
    __syncthreads();

    short8 af[4], bf_[4];
#pragma unroll
    for (int i = 0; i < 4; ++i) {
      af[i]  = *(const short8*)&As[aoff[i]];
      bf_[i] = *(const short8*)&Bs[boff[i]];
    }
#pragma unroll
    for (int mi = 0; mi < 4; ++mi)
#pragma unroll
      for (int ni = 0; ni < 4; ++ni)
        acc[mi][ni] = __builtin_amdgcn_mfma_f32_16x16x32_bf16(af[mi], bf_[ni], acc[mi][ni], 0, 0, 0);
  }

  const size_t hrow0 = (size_t)rbase + mt * 128;
#pragma unroll
  for (int mi = 0; mi < 4; ++mi) {
#pragma unroll
    for (int ni = 0; ni < 4; ++ni) {
      int gn = nt * 128 + wn * 64 + ni * 16 + l15;
      float bias = b1[e * DF + gn];
      int r0 = wm * 64 + mi * 16 + l4 * 4;
#pragma unroll
      for (int j = 0; j < 4; ++j) {
        float v = acc[mi][ni][j] + bias;
        v = 0.5f * v * (1.0f + erff(v * 0.70710678118654752f));
        H[(hrow0 + r0 + j) * DF + gn] = f2bf(v);
      }
    }
  }
}

// ---------------- FFN2: per-slot Y (no atomics) or atomic fallback ----------------
template <bool USEY>
__global__ __launch_bounds__(256) void ffn2_k(const u16* __restrict__ H,
                                              const u16* __restrict__ W2T,
                                              const float* __restrict__ b2,
                                              const int* __restrict__ lt,
                                              const float* __restrict__ lw,
                                              const int* __restrict__ meta,
                                              float* __restrict__ Y,
                                              float* __restrict__ out) {
  const int e = blockIdx.z, mt = blockIdx.y, nt = blockIdx.x;
  const int pc = meta[8 + e];
  if (mt * 128 >= pc) return;
  const int rbase = meta[16 + e];

  __shared__ u16 As[128 * 32];
  __shared__ u16 Bs[128 * 32];
  __shared__ int s_ts[128];
  __shared__ float s_w[128];

  const int tid = threadIdx.x, lane = tid & 63, wv = tid >> 6;
  const int wm = wv >> 1, wn = wv & 1, l15 = lane & 15, l4 = lane >> 4;

  if (tid < 128) {
    s_ts[tid] = lt[e * NT + mt * 128 + tid];
    s_w[tid]  = lw[e * NT + mt * 128 + tid];
  }

  const u16* pa[2]; const u16* pb[2]; u16* la[2]; u16* lb[2];
#pragma unroll
  for (int it = 0; it < 2; ++it) {
    int idx = it * 256 + tid;
    int r = idx >> 2, s = idx & 3;
    int kg = s ^ ((r >> 1) & 3);
    pa[it] = H + ((size_t)rbase + mt * 128 + r) * DF + kg * 8;
    pb[it] = W2T + ((size_t)e * DM + nt * 128 + r) * DF + kg * 8;
    la[it] = As + (it * 256 + wv * 64) * 8;
    lb[it] = Bs + (it * 256 + wv * 64) * 8;
  }

  int aoff[4], boff[4];
#pragma unroll
  for (int i = 0; i < 4; ++i) {
    int ra = wm * 64 + i * 16 + l15;
    aoff[i] = ra * 32 + (l4 ^ ((ra >> 1) & 3)) * 8;
    int rb = wn * 64 + i * 16 + l15;
    boff[i] = rb * 32 + (l4 ^ ((rb >> 1) & 3)) * 8;
  }

  f32x4 acc[4][4];
#pragma unroll
  for (int mi = 0; mi < 4; ++mi)
#pragma unroll
    for (int ni = 0; ni < 4; ++ni) acc[mi][ni] = 0.f;

  for (int ks = 0; ks < DF / 32; ++ks) {
    __syncthreads();
    gload16(pa[0], la[0]); gload16(pa[1], la[1]);
    gload16(pb[0], lb[0]); gload16(pb[1], lb[1]);
    pa[0] += 32; pa[1] += 32; pb[0] += 32; pb[1] += 32;
    __syncthreads();

    short8 af[4], bf_[4];
#pragma unroll
    for (int i = 0; i < 4; ++i) {
      af[i]  = *(const short8*)&As[aoff[i]];
      bf_[i] = *(const short8*)&Bs[boff[i]];
    }
#pragma unroll
    for (int mi = 0; mi < 4; ++mi)
#pragma unroll
      for (int ni = 0; ni < 4; ++ni)
        acc[mi][ni] = __builtin_amdgcn_mfma_f32_16x16x32_bf16(af[mi], bf_[ni], acc[mi][ni], 0, 0, 0);
  }

#pragma unroll
  for (int mi = 0; mi < 4; ++mi) {
#pragma unroll
    for (int ni = 0; ni < 4; ++ni) {
      int gn = nt * 128 + wn * 64 + ni * 16 + l15;
      float bias = b2[e * DM + gn];
      int r0 = wm * 64 + mi * 16 + l4 * 4;
#pragma unroll
      for (int j = 0; j < 4; ++j) {
        int r = r0 + j;
        float w = s_w[r];
        int ts = s_ts[r];
        float v = w * (acc[mi][ni][j] + bias);
        if (USEY) {
          Y[(size_t)ts * DM + gn] = v;
        } else {
          int tok = ts >> 1;
          if (tok >= NT) tok = 0;        // dummy adds w=0 -> +0.0
          atomicAdd(out + (size_t)tok * DM + gn, v);
        }
      }
    }
  }
}

// ---------------- combine: out[t] = Y[2t] + Y[2t+1] ----------------
__global__ __launch_bounds__(256) void combine_k(const float* __restrict__ Y,
                                                 float* __restrict__ out) {
  size_t i4 = (size_t)blockIdx.x * 256 + threadIdx.x;
  size_t t = i4 >> 8;
  int c4 = (int)(i4 & 255) * 4;
  const float4 a = *(const float4*)(Y + (2 * t) * DM + c4);
  const float4 b = *(const float4*)(Y + (2 * t + 1) * DM + c4);
  float4 o = { a.x + b.x, a.y + b.y, a.z + b.z, a.w + b.w };
  *(float4*)(out + t * DM + c4) = o;
}

extern "C" void kernel_launch(void* const* d_in, const int* in_sizes, int n_in,
                              void* d_out, int out_size, void* d_ws, size_t ws_size,
                              hipStream_t stream) {
  const float* x  = (const float*)d_in[0];
  const float* Wg = (const float*)d_in[1];
  const float* W1 = (const float*)d_in[2];
  const float* b1 = (const float*)d_in[3];
  const float* W2 = (const float*)d_in[4];
  const float* b2 = (const float*)d_in[5];
  float* out = (float*)d_out;

  char* ws = (char*)d_ws;
  size_t o = 0;
  auto take = [&](size_t sz) { size_t p = o; o = (o + sz + 1023) & ~(size_t)1023; return p; };

  int*   meta = (int*)(ws + take(1024));
  int*   te   = (int*)(ws + take((size_t)NT * 2 * 4));
  float* tw   = (float*)(ws + take((size_t)NT * 2 * 4));
  int*   lt   = (int*)(ws + take((size_t)NE * NT * 4));
  float* lw   = (float*)(ws + take((size_t)NE * NT * 4));
  u16*   xbf  = (u16*)(ws + take((size_t)NT * DM * 2));
  u16*   W1T  = (u16*)(ws + take((size_t)NE * DM * DF * 2));
  u16*   H    = (u16*)(ws + take((size_t)HROWS * DF * 2));
  size_t needB = o;
  size_t needA = needB + ((size_t)NE * DM * DF * 2 + 1024) + ((size_t)(2 * NT + 8) * DM * 4 + 1024);

  bool pathA = (ws_size >= needA);
  u16*   W2T;
  float* Y = nullptr;
  if (pathA) {
    W2T = (u16*)(ws + take((size_t)NE * DM * DF * 2));
    Y   = (float*)(ws + take((size_t)(2 * NT + 8) * DM * 4));
  } else {
    W2T = W1T;   // alias: converted between ffn1 and ffn2
  }

  hipMemsetAsync(meta, 0, 1024, stream);
  if (!pathA) hipMemsetAsync(out, 0, (size_t)NT * DM * 4, stream);

  gate_k<<<NT / 4, 256, 0, stream>>>(x, Wg, te, tw);
  route_k<<<(NT * 2) / 256, 256, 0, stream>>>(te, tw, meta, lt, lw);
  finalize_k<<<1, 256, 0, stream>>>(meta, lt, lw);
  prep_x<<<(NT * DM / 8) / 256, 256, 0, stream>>>(x, xbf);
  prep_wT<<<dim3(DF / 64, DM / 64, NE), 256, 0, stream>>>(W1, W1T, DM, DF);
  if (pathA)
    prep_wT<<<dim3(DM / 64, DF / 64, NE), 256, 0, stream>>>(W2, W2T, DF, DM);

  ffn1_k<<<dim3(DF / 128, NT / 128, NE), 256, 0, stream>>>(xbf, W1T, b1, lt, meta, H);

  if (!pathA)
    prep_wT<<<dim3(DM / 64, DF / 64, NE), 256, 0, stream>>>(W2, W2T, DF, DM);

  if (pathA) {
    ffn2_k<true><<<dim3(DM / 128, NT / 128, NE), 256, 0, stream>>>(H, W2T, b2, lt, lw, meta, Y, out);
    combine_k<<<NT, 256, 0, stream>>>(Y, out);
  } else {
    ffn2_k<false><<<dim3(DM / 128, NT / 128, NE), 256, 0, stream>>>(H, W2T, b2, lt, lw, meta, Y, out);
  }
}